// Round 14
// baseline (267.314 us; speedup 1.0000x reference)
//
#include <hip/hip_runtime.h>

typedef __attribute__((ext_vector_type(8))) short short8;
typedef __attribute__((ext_vector_type(4))) float f32x4;
typedef __attribute__((ext_vector_type(4))) unsigned int u32x4;
typedef __attribute__((ext_vector_type(2))) unsigned int u32x2;
typedef __attribute__((ext_vector_type(4))) unsigned short u16x4;

#define NHEADS 16
#define DHEAD 64
#define SEQ 2048
#define BATCH 4
#define HD 1024
#define MTOT 8192  // BATCH*SEQ

// RNE f32->bf16 (cold paths)
static __device__ __forceinline__ unsigned short f2b(float x) {
  unsigned u = __builtin_bit_cast(unsigned, x);
  u += 0x7fffu + ((u >> 16) & 1u);
  return (unsigned short)(u >> 16);
}

// round-half-up pack of two f32 -> bf16x2 (<=0.5 ulp, 4 insts; hot paths)
static __device__ __forceinline__ unsigned pk2h(float lo, float hi) {
  unsigned a = __builtin_bit_cast(unsigned, lo) + 0x8000u;
  unsigned b = __builtin_bit_cast(unsigned, hi) + 0x8000u;
  return (a >> 16) | (b & 0xffff0000u);
}

// async global -> LDS, 16B per lane. LDS dst = wave-uniform base + lane*16.
static __device__ __forceinline__ void gll16(const void* g, void* l) {
  __builtin_amdgcn_global_load_lds(
      (const __attribute__((address_space(1))) unsigned int*)g,
      (__attribute__((address_space(3))) unsigned int*)l, 16, 0, 0);
}

// ---------------- f32 -> bf16 conversion (hidden states) ----------------
__global__ void cvt_bf16(const float* __restrict__ src,
                         unsigned short* __restrict__ dst, int n4) {
  int i = blockIdx.x * blockDim.x + threadIdx.x;
  if (i < n4) {
    f32x4 v = ((const f32x4*)src)[i];
    u16x4 o;
    o[0] = f2b(v[0]); o[1] = f2b(v[1]); o[2] = f2b(v[2]); o[3] = f2b(v[3]);
    ((u16x4*)dst)[i] = o;
  }
}

// ---- combined prep: Wq/Wk/Wv -> bf16, wmask = bf16(exp(mask)) ----
#define WQ4 (HD * HD / 4)   // 262144 vec4s per weight matrix
__global__ void prep(const float* __restrict__ Wq, const float* __restrict__ Wk,
                     const float* __restrict__ Wv, const float* __restrict__ mask,
                     unsigned short* __restrict__ Wb,
                     unsigned short* __restrict__ Wm) {
  int i = blockIdx.x * blockDim.x + threadIdx.x;
  if (i < 3 * WQ4) {
    int rg = i / WQ4;
    int idx = i - rg * WQ4;
    const float* src = (rg == 0) ? Wq : (rg == 1) ? Wk : Wv;
    f32x4 v = ((const f32x4*)src)[idx];
    u16x4 o;
    o[0] = f2b(v[0]); o[1] = f2b(v[1]); o[2] = f2b(v[2]); o[3] = f2b(v[3]);
    ((u16x4*)(Wb + (size_t)rg * HD * HD))[idx] = o;
  } else {
    int j = i - 3 * WQ4;            // 0..2047 vec4s of mask
    f32x4 v = ((const f32x4*)mask)[j];
    u16x4 o;
    o[0] = f2b(__expf(v[0])); o[1] = f2b(__expf(v[1]));
    o[2] = f2b(__expf(v[2])); o[3] = f2b(__expf(v[3]));
    ((u16x4*)Wm)[j] = o;
  }
}

// ------- fused QKV GEMM: 128x128, 256 thr, m97 single-buffer structure -----
// R16: SINGLE 32KB buffer, per K-step
//   {barrier -> stage 8 gll16/thr -> barrier(vmcnt0 drain) -> 32 MFMA};
// VGPR 108 + 32KB LDS -> 4 blocks/CU; drain stall of one block hides under
// other blocks' MFMA (m114 implicit overlap). Validated R16: qkv 96.5 -> <91.
// Per-wave (1M x 4N): 128 rows x 32 cols -> acc[8][2]=64 VGPR, bf[2][2]=16,
// af[2] transient -- fits the 128-VGPR/4-wave budget (R9-R12 lesson: bigger
// blocks get VGPR-pinned and spill; 256 thr allocates pressure-driven).
// R8 kept: m-slab XCD swizzle (8 m-tiles/XCD: X slab L2-resident, W panel
// fetched ~once/XCD -> FETCH 50MB), pre-swizzled-global gather so gll16's
// linear LDS write lands the XOR [row][slot s^=r&7] layout (0 conflicts).
__global__ __launch_bounds__(256) void qkv_gemm(
    const unsigned short* __restrict__ X,
    const unsigned short* __restrict__ Wall,
    const float* __restrict__ bq, const float* __restrict__ bk,
    const float* __restrict__ bv,
    const float* __restrict__ rel,          // [2048][64] f32
    const float* __restrict__ mask,         // [4][2048] f32
    unsigned short* __restrict__ Qo,
    unsigned short* __restrict__ Ko,
    unsigned short* __restrict__ Vt) {
  __shared__ __align__(16) unsigned short As[128 * 64];
  __shared__ __align__(16) unsigned short Bs[128 * 64];

  const int t = threadIdx.x;           // 0..255
  const int lane = t & 63;
  const int w = t >> 6;                // 0..3 == wn (N strip)

  // XCD swizzle: 8 m-tiles pinned per XCD (2MB X slab, L2-resident);
  // consecutive li share a panel so each W panel is fetched ~once per XCD.
  const int n = blockIdx.x;            // 0..1535
  const int xcd = n & 7;
  const int li = n >> 3;               // 0..191
  const int bx = xcd * 8 + (li & 7);   // m-tile 0..63
  const int pp = li >> 3;              // 0..23
  const int by = pp & 7;               // n-tile 0..7
  const int bz = pp >> 3;              // 0=Q 1=K 2=V

  const unsigned short* Wp = Wall + (size_t)bz * HD * HD;
  const int m0 = bx * 128;
  const int n0 = by * 128;

  const int cl = lane & 15;
  const int qd = lane >> 4;

  f32x4 acc[8][2];
#pragma unroll
  for (int i = 0; i < 8; i++)
#pragma unroll
    for (int j = 0; j < 2; j++) acc[i][j] = (f32x4){0.f, 0.f, 0.f, 0.f};

  // stage one 4KB unit = rows q*32..q*32+31, 64 k. Thread t -> row
  // q*32 + (t>>3), global chunk (t&7)^(row&7); LDS write is linear so
  // slot (t&7) at that row holds chunk (t&7)^(row&7) == XOR layout.
  auto stageA = [&](int q, int k0) {
    int rr = (q << 5) + (t >> 3);
    gll16(X + (size_t)(m0 + rr) * HD + k0 + (((t & 7) ^ (rr & 7)) << 3),
          &As[((q << 5) + (w << 3)) * 64]);
  };
  auto stageB = [&](int q, int k0) {
    int rr = (q << 5) + (t >> 3);
    gll16(Wp + (size_t)(n0 + rr) * HD + k0 + (((t & 7) ^ (rr & 7)) << 3),
          &Bs[((q << 5) + (w << 3)) * 64]);
  };

#pragma unroll 1
  for (int it = 0; it < 16; it++) {
    const int k0 = it * 64;
    __syncthreads();   // prev iter's LDS reads done before overwrite
    stageA(0, k0); stageA(1, k0); stageA(2, k0); stageA(3, k0);
    stageB(0, k0); stageB(1, k0); stageB(2, k0); stageB(3, k0);
    __syncthreads();   // drains vmcnt(0): tile landed + visible

    // bf for this wave's 32 B-rows, both K-halves (held through iter)
    short8 bf[2][2];
#pragma unroll
    for (int j = 0; j < 2; j++) {
      int r = w * 32 + j * 16 + cl;
      const unsigned short* rp = &Bs[r * 64];
#pragma unroll
      for (int ks = 0; ks < 2; ks++)
        bf[j][ks] = *(const short8*)(rp + (((ks * 4 + qd) ^ (r & 7)) << 3));
    }

    __builtin_amdgcn_s_setprio(1);
#pragma unroll
    for (int mq = 0; mq < 4; mq++) {
#pragma unroll
      for (int ks = 0; ks < 2; ks++) {
        short8 af[2];
#pragma unroll
        for (int i = 0; i < 2; i++) {
          int r = mq * 32 + i * 16 + cl;
          af[i] = *(const short8*)(&As[r * 64] +
                                   (((ks * 4 + qd) ^ (r & 7)) << 3));
        }
        if (bz < 2) {
#pragma unroll
          for (int i = 0; i < 2; i++)
#pragma unroll
            for (int j = 0; j < 2; j++)
              acc[mq * 2 + i][j] = __builtin_amdgcn_mfma_f32_16x16x32_bf16(
                  bf[j][ks], af[i], acc[mq * 2 + i][j], 0, 0, 0);
        } else {
#pragma unroll
          for (int i = 0; i < 2; i++)
#pragma unroll
            for (int j = 0; j < 2; j++)
              acc[mq * 2 + i][j] = __builtin_amdgcn_mfma_f32_16x16x32_bf16(
                  af[i], bf[j][ks], acc[mq * 2 + i][j], 0, 0, 0);
        }
      }
    }
    __builtin_amdgcn_s_setprio(0);
  }

  // ---- epilogue (per-wave 128 rows x 32 cols at (m0, n0 + w*32)) ----
  if (bz == 2) {
    // normal orientation: acc[mf][nf] = D[m(s)][n(feature)]
#pragma unroll
    for (int mf = 0; mf < 8; mf++) {
      int mb = m0 + mf * 16 + qd * 4;
      int bb = mb >> 11, ssb = mb & (SEQ - 1);
      f32x4 mk = *(const f32x4*)(mask + bb * SEQ + ssb);
      f32x4 w4;
#pragma unroll
      for (int r = 0; r < 4; r++) w4[r] = __expf(mk[r]);
      int colp = (ssb & ~31) | ((ssb & 12) << 1) | (((ssb >> 4) & 1) << 2);
#pragma unroll
      for (int nf = 0; nf < 2; nf++) {
        int feat = n0 + w * 32 + nf * 16 + cl;
        int hh = feat >> 6;
        int dd = feat & 63;
        float bn = bv[feat];
        u32x2 pk;
        pk[0] = pk2h((acc[mf][nf][0] + bn) * w4[0], (acc[mf][nf][1] + bn) * w4[1]);
        pk[1] = pk2h((acc[mf][nf][2] + bn) * w4[2], (acc[mf][nf][3] + bn) * w4[3]);
        *(u32x2*)(Vt + ((size_t)((bb * NHEADS + hh) * DHEAD + dd)) * SEQ + colp) = pk;
      }
    }
  } else {
    // transposed: acc[mf][nf] = D[n(feature)][m(s)]
    const float* bias = (bz == 0) ? bq : bk;
    unsigned short* Out = (bz == 0) ? Qo : Ko;
    const float qs = (bz == 0) ? 0.125f * 1.4426950408889634f : 1.0f;
#pragma unroll
    for (int nf = 0; nf < 2; nf++) {
      int feat0 = n0 + w * 32 + nf * 16 + qd * 4;
      int hh = feat0 >> 6;
      int ddb = feat0 & 63;
      f32x4 b4 = *(const f32x4*)(bias + feat0);
#pragma unroll
      for (int mf = 0; mf < 8; mf++) {
        int s = m0 + mf * 16 + cl;
        int bb = s >> 11, ss = s & (SEQ - 1);
        f32x4 rl = *(const f32x4*)(rel + ss * DHEAD + ddb);
        float x0 = acc[mf][nf][0] + b4[0];
        float x1 = acc[mf][nf][1] + b4[1];
        float x2 = acc[mf][nf][2] + b4[2];
        float x3 = acc[mf][nf][3] + b4[3];
        float y0 = (x0 * rl[1] - x1 * rl[0]) * qs;
        float y1 = (x1 * rl[1] + x0 * rl[0]) * qs;
        float y2 = (x2 * rl[3] - x3 * rl[2]) * qs;
        float y3 = (x3 * rl[3] + x2 * rl[2]) * qs;
        u32x2 pk;
        pk[0] = pk2h(y0, y1);
        pk[1] = pk2h(y2, y3);
        *(u32x2*)(Out + (((size_t)(bb * NHEADS + hh)) * SEQ + ss) * DHEAD + ddb) = pk;
      }
    }
  }
}

// ---------------- flash attention ----------------
// Q: [64][2048][64] bf16 pre-scaled by 0.125*log2e; K: [64][2048][64] bf16;
// Vt: [64][64][2048] bf16 (columns permuted, mask-scaled); wm: [4][2048] bf16.
// out: [4][2048][1024] f32.  Softmax inner op = one exp2 per score.
//
// R18 (3rd submission -- R12/R13 both died on container acquisition, never
// ran): halve per-wave q-rows 32->16 (grid 1024->2048, q-tile 64 rows).
// R17's softmax-fusion failed to move VGPR/occupancy (live-range massaging
// isn't binding); this is a STRUCTURAL register cut: per-wave held state
// sc32+pw16+ov16+ovl4+qf8 ~= 76 regs (was ~120) -> more waves/SIMD.
// Total MFMA/VALU work unchanged; K/V tiles read by 2x blocks (L2-resident,
// XCD-pinned). Sync structure = R16's proven single-buffer restage:
//   top barrier [K landed] -> stageV -> QK^T + softmax (covers V latency)
//   -> vmcnt(0)+barrier [V visible] -> stageK(it+1) -> PV.
__global__ __launch_bounds__(256, 2) void attn(
    const unsigned short* __restrict__ Q,
    const unsigned short* __restrict__ K,
    const unsigned short* __restrict__ Vt,
    const unsigned short* __restrict__ wmask,
    float* __restrict__ out) {
  __shared__ __align__(16) unsigned short Ks[128 * 64];   // [key][d], swizzled
  __shared__ __align__(16) unsigned short Vs[64 * 128];   // [d][key'], swizzled

  const int t = threadIdx.x;
  const int lane = t & 63;
  const int w = t >> 6;

  // XCD swizzle: all 32 q-tiles of a bh on one XCD
  const int n = blockIdx.x;          // 0..2047
  const int xcd = n & 7;
  const int li = n >> 3;             // 0..255
  const int bh = xcd * 8 + (li >> 5);
  const int qt = li & 31;

  const int b = bh >> 4, h = bh & 15;
  const int s0 = qt * 64;
  const unsigned short* Qp = Q + (size_t)bh * SEQ * DHEAD;
  const unsigned short* Kp = K + (size_t)bh * SEQ * DHEAD;
  const unsigned short* Vp = Vt + (size_t)bh * DHEAD * SEQ;
  const unsigned short* wmp = wmask + b * SEQ;

  const int cl = lane & 15;
  const int qd = lane >> 4;

  short8 qf[2];   // 16 q-rows: s0 + w*16 + cl
#pragma unroll
  for (int ks = 0; ks < 2; ks++)
    qf[ks] = *(const short8*)(Qp + (size_t)(s0 + w * 16 + cl) * DHEAD +
                              ks * 32 + qd * 8);

  f32x4 ov[4];   // [dt], D[d][q]: q=cl, d rows = dt*16+qd*4+r
  f32x4 ovl;     // l accumulator (sum_k w_k p_k), all rows identical
  ovl = (f32x4){0.f, 0.f, 0.f, 0.f};
#pragma unroll
  for (int dt = 0; dt < 4; dt++) ov[dt] = (f32x4){0.f, 0.f, 0.f, 0.f};

  auto stageK = [&](int kt) {
#pragma unroll
    for (int j = 0; j < 4; j++) {
      int r0 = w * 32 + j * 8;
      int r = r0 + (lane >> 3);
      int c = (lane & 7) ^ (r & 7);
      gll16(Kp + (size_t)(kt + r) * DHEAD + c * 8, &Ks[r0 * 64]);
    }
  };
  auto stageV = [&](int kt) {
#pragma unroll
    for (int j = 0; j < 4; j++) {
      int r0 = w * 16 + j * 4;
      int r = r0 + (lane >> 4);
      int c = (lane & 15) ^ (r & 7);
      gll16(Vp + (size_t)r * SEQ + kt + c * 8, &Vs[r0 * 128]);
    }
  };

  stageK(0);

  for (int it = 0; it < SEQ / 128; it++) {
    const int kt = it * 128;
    __syncthreads();      // K(it) landed+visible; prev PV reads done
    stageV(kt);           // V(it) -> Vs (async; used after softmax)

    // w A-fragment for l-MFMA: keys in P's permuted k-order
    short8 wf[4];
#pragma unroll
    for (int c = 0; c < 4; c++) {
      u32x2 w0 = *(const u32x2*)(wmp + kt + c * 32 + qd * 4);
      u32x2 w1 = *(const u32x2*)(wmp + kt + c * 32 + 16 + qd * 4);
      u32x4 ww = {w0[0], w0[1], w1[0], w1[1]};
      wf[c] = __builtin_bit_cast(short8, ww);
    }

    // ---- scores: D[m=key][n=q] ----
    f32x4 sc[8];
#pragma unroll
    for (int nt = 0; nt < 8; nt++) sc[nt] = (f32x4){0.f, 0.f, 0.f, 0.f};
#pragma unroll
    for (int ks = 0; ks < 2; ks++) {
#pragma unroll
      for (int nt = 0; nt < 8; nt++) {
        int krow = nt * 16 + cl;
        short8 kf = *(const short8*)(Ks + krow * 64 +
                                     (((ks * 4 + qd) ^ (krow & 7)) << 3));
        sc[nt] = __builtin_amdgcn_mfma_f32_16x16x32_bf16(kf, qf[ks], sc[nt], 0, 0, 0);
      }
    }

    // ---- softmax: p = exp2(s) ----
    unsigned pw[8][2];
#pragma unroll
    for (int nt = 0; nt < 8; nt++) {
      float p0 = __builtin_amdgcn_exp2f(sc[nt][0]);
      float p1 = __builtin_amdgcn_exp2f(sc[nt][1]);
      float p2 = __builtin_amdgcn_exp2f(sc[nt][2]);
      float p3 = __builtin_amdgcn_exp2f(sc[nt][3]);
      pw[nt][0] = pk2h(p0, p1);
      pw[nt][1] = pk2h(p2, p3);
    }

    // ---- V(it) landed + visible; then issue K(it+1) ----
    __builtin_amdgcn_sched_barrier(0);
    asm volatile("s_waitcnt vmcnt(0)");   // drains V (+wf; K not in flight)
    __builtin_amdgcn_sched_barrier(0);
    __builtin_amdgcn_s_barrier();         // all waves' V writes visible
    __builtin_amdgcn_sched_barrier(0);

    if (it + 1 < SEQ / 128) stageK(kt + 128);  // after all QK reads of Ks

    // ---- O += V' * P (permuted k-order; V from single-buffer LDS) ----
#pragma unroll
    for (int c = 0; c < 4; c++) {
      u32x4 bb0 = {pw[2 * c][0], pw[2 * c][1], pw[2 * c + 1][0], pw[2 * c + 1][1]};
      short8 bf0 = __builtin_bit_cast(short8, bb0);
      ovl = __builtin_amdgcn_mfma_f32_16x16x32_bf16(wf[c], bf0, ovl, 0, 0, 0);
#pragma unroll
      for (int dt = 0; dt < 4; dt++) {
        int vrow = dt * 16 + cl;
        short8 vf = *(const short8*)(Vs + vrow * 128 +
                                     (((c * 4 + qd) ^ (vrow & 7)) << 3));
        ov[dt] = __builtin_amdgcn_mfma_f32_16x16x32_bf16(vf, bf0, ov[dt], 0, 0, 0);
      }
    }
  }

  // ---- epilogue: O[d][q] / l(q) ----
  {
    float rl = 1.0f / ovl[0];
    int s = s0 + w * 16 + cl;
    float* ob = out + ((size_t)b * SEQ + s) * HD + h * DHEAD;
#pragma unroll
    for (int dt = 0; dt < 4; dt++) {
      f32x4 o;
      o[0] = ov[dt][0] * rl;
      o[1] = ov[dt][1] * rl;
      o[2] = ov[dt][2] * rl;
      o[3] = ov[dt][3] * rl;
      *(f32x4*)(ob + dt * 16 + qd * 4) = o;
    }
  }
}

extern "C" void kernel_launch(void* const* d_in, const int* in_sizes, int n_in,
                              void* d_out, int out_size, void* d_ws, size_t ws_size,
                              hipStream_t stream) {
  const float* hidden = (const float*)d_in[0];
  const float* mask   = (const float*)d_in[1];
  const float* rel    = (const float*)d_in[2];
  const float* Wq     = (const float*)d_in[3];
  const float* bq     = (const float*)d_in[4];
  const float* Wk     = (const float*)d_in[5];
  const float* bk     = (const float*)d_in[6];
  const float* Wv     = (const float*)d_in[7];
  const float* bv     = (const float*)d_in[8];
  float* out = (float*)d_out;

  unsigned short* Xb = (unsigned short*)d_ws;          // 8192*1024
  unsigned short* Wb = Xb + (size_t)MTOT * HD;         // 3*1024*1024
  unsigned short* Qb = Wb + (size_t)3 * HD * HD;       // 8192*1024
  unsigned short* Kb = Qb + (size_t)MTOT * HD;
  unsigned short* Vb = Kb + (size_t)MTOT * HD;
  unsigned short* Wm = Vb + (size_t)MTOT * HD;         // 4*2048

  {
    int n4 = MTOT * HD / 4;
    cvt_bf16<<<n4 / 256, 256, 0, stream>>>(hidden, Xb, n4);
  }
  prep<<<(3 * WQ4 + BATCH * SEQ / 4) / 256, 256, 0, stream>>>(Wq, Wk, Wv, mask, Wb, Wm);
  qkv_gemm<<<dim3(1536), 256, 0, stream>>>(Xb, Wb, bq, bk, bv, rel, mask, Qb, Kb, Vb);
  attn<<<dim3(2048), 256, 0, stream>>>(Qb, Kb, Vb, Wm, out);
}

// Round 15
// 256.961 us; speedup vs baseline: 1.0403x; 1.0403x over previous
//
#include <hip/hip_runtime.h>

typedef __attribute__((ext_vector_type(8))) short short8;
typedef __attribute__((ext_vector_type(4))) float f32x4;
typedef __attribute__((ext_vector_type(4))) unsigned int u32x4;
typedef __attribute__((ext_vector_type(2))) unsigned int u32x2;
typedef __attribute__((ext_vector_type(4))) unsigned short u16x4;

#define NHEADS 16
#define DHEAD 64
#define SEQ 2048
#define BATCH 4
#define HD 1024
#define MTOT 8192  // BATCH*SEQ

// RNE f32->bf16 (cold paths)
static __device__ __forceinline__ unsigned short f2b(float x) {
  unsigned u = __builtin_bit_cast(unsigned, x);
  u += 0x7fffu + ((u >> 16) & 1u);
  return (unsigned short)(u >> 16);
}

// round-half-up pack of two f32 -> bf16x2 (<=0.5 ulp, 4 insts; hot paths)
static __device__ __forceinline__ unsigned pk2h(float lo, float hi) {
  unsigned a = __builtin_bit_cast(unsigned, lo) + 0x8000u;
  unsigned b = __builtin_bit_cast(unsigned, hi) + 0x8000u;
  return (a >> 16) | (b & 0xffff0000u);
}

// async global -> LDS, 16B per lane. LDS dst = wave-uniform base + lane*16.
static __device__ __forceinline__ void gll16(const void* g, void* l) {
  __builtin_amdgcn_global_load_lds(
      (const __attribute__((address_space(1))) unsigned int*)g,
      (__attribute__((address_space(3))) unsigned int*)l, 16, 0, 0);
}

// ---------------- f32 -> bf16 conversion (hidden states) ----------------
__global__ void cvt_bf16(const float* __restrict__ src,
                         unsigned short* __restrict__ dst, int n4) {
  int i = blockIdx.x * blockDim.x + threadIdx.x;
  if (i < n4) {
    f32x4 v = ((const f32x4*)src)[i];
    u16x4 o;
    o[0] = f2b(v[0]); o[1] = f2b(v[1]); o[2] = f2b(v[2]); o[3] = f2b(v[3]);
    ((u16x4*)dst)[i] = o;
  }
}

// ---- combined prep: Wq/Wk/Wv -> bf16, wmask = bf16(exp(mask)) ----
#define WQ4 (HD * HD / 4)   // 262144 vec4s per weight matrix
__global__ void prep(const float* __restrict__ Wq, const float* __restrict__ Wk,
                     const float* __restrict__ Wv, const float* __restrict__ mask,
                     unsigned short* __restrict__ Wb,
                     unsigned short* __restrict__ Wm) {
  int i = blockIdx.x * blockDim.x + threadIdx.x;
  if (i < 3 * WQ4) {
    int rg = i / WQ4;
    int idx = i - rg * WQ4;
    const float* src = (rg == 0) ? Wq : (rg == 1) ? Wk : Wv;
    f32x4 v = ((const f32x4*)src)[idx];
    u16x4 o;
    o[0] = f2b(v[0]); o[1] = f2b(v[1]); o[2] = f2b(v[2]); o[3] = f2b(v[3]);
    ((u16x4*)(Wb + (size_t)rg * HD * HD))[idx] = o;
  } else {
    int j = i - 3 * WQ4;            // 0..2047 vec4s of mask
    f32x4 v = ((const f32x4*)mask)[j];
    u16x4 o;
    o[0] = f2b(__expf(v[0])); o[1] = f2b(__expf(v[1]));
    o[2] = f2b(__expf(v[2])); o[3] = f2b(__expf(v[3]));
    ((u16x4*)Wm)[j] = o;
  }
}

// ------- fused QKV GEMM: 128x128, 256 thr, m97 single-buffer structure -----
// R16 (unchanged): SINGLE 32KB buffer, per K-step
//   {barrier -> stage 8 gll16/thr -> barrier(vmcnt0 drain) -> 32 MFMA};
// VGPR 108 + 32KB LDS -> 4 blocks/CU; drain stall of one block hides under
// other blocks' MFMA (m114 implicit overlap). Validated R16: qkv 96.5 -> <91.
// Per-wave (1M x 4N): 128 rows x 32 cols -> acc[8][2]=64 VGPR, bf[2][2]=16,
// af[2] transient -- fits the 128-VGPR/4-wave budget (R9-R12 lesson: bigger
// blocks get VGPR-pinned and spill; 256 thr allocates pressure-driven).
// R8 kept: m-slab XCD swizzle (8 m-tiles/XCD: X slab L2-resident, W panel
// fetched ~once/XCD -> FETCH 50MB), pre-swizzled-global gather so gll16's
// linear LDS write lands the XOR [row][slot s^=r&7] layout (0 conflicts).
__global__ __launch_bounds__(256) void qkv_gemm(
    const unsigned short* __restrict__ X,
    const unsigned short* __restrict__ Wall,
    const float* __restrict__ bq, const float* __restrict__ bk,
    const float* __restrict__ bv,
    const float* __restrict__ rel,          // [2048][64] f32
    const float* __restrict__ mask,         // [4][2048] f32
    unsigned short* __restrict__ Qo,
    unsigned short* __restrict__ Ko,
    unsigned short* __restrict__ Vt) {
  __shared__ __align__(16) unsigned short As[128 * 64];
  __shared__ __align__(16) unsigned short Bs[128 * 64];

  const int t = threadIdx.x;           // 0..255
  const int lane = t & 63;
  const int w = t >> 6;                // 0..3 == wn (N strip)

  // XCD swizzle: 8 m-tiles pinned per XCD (2MB X slab, L2-resident);
  // consecutive li share a panel so each W panel is fetched ~once per XCD.
  const int n = blockIdx.x;            // 0..1535
  const int xcd = n & 7;
  const int li = n >> 3;               // 0..191
  const int bx = xcd * 8 + (li & 7);   // m-tile 0..63
  const int pp = li >> 3;              // 0..23
  const int by = pp & 7;               // n-tile 0..7
  const int bz = pp >> 3;              // 0=Q 1=K 2=V

  const unsigned short* Wp = Wall + (size_t)bz * HD * HD;
  const int m0 = bx * 128;
  const int n0 = by * 128;

  const int cl = lane & 15;
  const int qd = lane >> 4;

  f32x4 acc[8][2];
#pragma unroll
  for (int i = 0; i < 8; i++)
#pragma unroll
    for (int j = 0; j < 2; j++) acc[i][j] = (f32x4){0.f, 0.f, 0.f, 0.f};

  // stage one 4KB unit = rows q*32..q*32+31, 64 k. Thread t -> row
  // q*32 + (t>>3), global chunk (t&7)^(row&7); LDS write is linear so
  // slot (t&7) at that row holds chunk (t&7)^(row&7) == XOR layout.
  auto stageA = [&](int q, int k0) {
    int rr = (q << 5) + (t >> 3);
    gll16(X + (size_t)(m0 + rr) * HD + k0 + (((t & 7) ^ (rr & 7)) << 3),
          &As[((q << 5) + (w << 3)) * 64]);
  };
  auto stageB = [&](int q, int k0) {
    int rr = (q << 5) + (t >> 3);
    gll16(Wp + (size_t)(n0 + rr) * HD + k0 + (((t & 7) ^ (rr & 7)) << 3),
          &Bs[((q << 5) + (w << 3)) * 64]);
  };

#pragma unroll 1
  for (int it = 0; it < 16; it++) {
    const int k0 = it * 64;
    __syncthreads();   // prev iter's LDS reads done before overwrite
    stageA(0, k0); stageA(1, k0); stageA(2, k0); stageA(3, k0);
    stageB(0, k0); stageB(1, k0); stageB(2, k0); stageB(3, k0);
    __syncthreads();   // drains vmcnt(0): tile landed + visible

    // bf for this wave's 32 B-rows, both K-halves (held through iter)
    short8 bf[2][2];
#pragma unroll
    for (int j = 0; j < 2; j++) {
      int r = w * 32 + j * 16 + cl;
      const unsigned short* rp = &Bs[r * 64];
#pragma unroll
      for (int ks = 0; ks < 2; ks++)
        bf[j][ks] = *(const short8*)(rp + (((ks * 4 + qd) ^ (r & 7)) << 3));
    }

    __builtin_amdgcn_s_setprio(1);
#pragma unroll
    for (int mq = 0; mq < 4; mq++) {
#pragma unroll
      for (int ks = 0; ks < 2; ks++) {
        short8 af[2];
#pragma unroll
        for (int i = 0; i < 2; i++) {
          int r = mq * 32 + i * 16 + cl;
          af[i] = *(const short8*)(&As[r * 64] +
                                   (((ks * 4 + qd) ^ (r & 7)) << 3));
        }
        if (bz < 2) {
#pragma unroll
          for (int i = 0; i < 2; i++)
#pragma unroll
            for (int j = 0; j < 2; j++)
              acc[mq * 2 + i][j] = __builtin_amdgcn_mfma_f32_16x16x32_bf16(
                  bf[j][ks], af[i], acc[mq * 2 + i][j], 0, 0, 0);
        } else {
#pragma unroll
          for (int i = 0; i < 2; i++)
#pragma unroll
            for (int j = 0; j < 2; j++)
              acc[mq * 2 + i][j] = __builtin_amdgcn_mfma_f32_16x16x32_bf16(
                  af[i], bf[j][ks], acc[mq * 2 + i][j], 0, 0, 0);
        }
      }
    }
    __builtin_amdgcn_s_setprio(0);
  }

  // ---- epilogue (per-wave 128 rows x 32 cols at (m0, n0 + w*32)) ----
  if (bz == 2) {
    // normal orientation: acc[mf][nf] = D[m(s)][n(feature)]
#pragma unroll
    for (int mf = 0; mf < 8; mf++) {
      int mb = m0 + mf * 16 + qd * 4;
      int bb = mb >> 11, ssb = mb & (SEQ - 1);
      f32x4 mk = *(const f32x4*)(mask + bb * SEQ + ssb);
      f32x4 w4;
#pragma unroll
      for (int r = 0; r < 4; r++) w4[r] = __expf(mk[r]);
      int colp = (ssb & ~31) | ((ssb & 12) << 1) | (((ssb >> 4) & 1) << 2);
#pragma unroll
      for (int nf = 0; nf < 2; nf++) {
        int feat = n0 + w * 32 + nf * 16 + cl;
        int hh = feat >> 6;
        int dd = feat & 63;
        float bn = bv[feat];
        u32x2 pk;
        pk[0] = pk2h((acc[mf][nf][0] + bn) * w4[0], (acc[mf][nf][1] + bn) * w4[1]);
        pk[1] = pk2h((acc[mf][nf][2] + bn) * w4[2], (acc[mf][nf][3] + bn) * w4[3]);
        *(u32x2*)(Vt + ((size_t)((bb * NHEADS + hh) * DHEAD + dd)) * SEQ + colp) = pk;
      }
    }
  } else {
    // transposed: acc[mf][nf] = D[n(feature)][m(s)]
    const float* bias = (bz == 0) ? bq : bk;
    unsigned short* Out = (bz == 0) ? Qo : Ko;
    const float qs = (bz == 0) ? 0.125f * 1.4426950408889634f : 1.0f;
#pragma unroll
    for (int nf = 0; nf < 2; nf++) {
      int feat0 = n0 + w * 32 + nf * 16 + qd * 4;
      int hh = feat0 >> 6;
      int ddb = feat0 & 63;
      f32x4 b4 = *(const f32x4*)(bias + feat0);
#pragma unroll
      for (int mf = 0; mf < 8; mf++) {
        int s = m0 + mf * 16 + cl;
        int bb = s >> 11, ss = s & (SEQ - 1);
        f32x4 rl = *(const f32x4*)(rel + ss * DHEAD + ddb);
        float x0 = acc[mf][nf][0] + b4[0];
        float x1 = acc[mf][nf][1] + b4[1];
        float x2 = acc[mf][nf][2] + b4[2];
        float x3 = acc[mf][nf][3] + b4[3];
        float y0 = (x0 * rl[1] - x1 * rl[0]) * qs;
        float y1 = (x1 * rl[1] + x0 * rl[0]) * qs;
        float y2 = (x2 * rl[3] - x3 * rl[2]) * qs;
        float y3 = (x3 * rl[3] + x2 * rl[2]) * qs;
        u32x2 pk;
        pk[0] = pk2h(y0, y1);
        pk[1] = pk2h(y2, y3);
        *(u32x2*)(Out + (((size_t)(bb * NHEADS + hh)) * SEQ + ss) * DHEAD + ddb) = pk;
      }
    }
  }
}

// ---------------- flash attention ----------------
// Q: [64][2048][64] bf16 pre-scaled by 0.125*log2e; K: [64][2048][64] bf16;
// Vt: [64][64][2048] bf16 (columns permuted, mask-scaled); wm: [4][2048] bf16.
// out: [4][2048][1024] f32.  Softmax inner op = one exp2 per score.
//
// R20: 512 thr / 8 waves x 16 q-rows = 128 q-rows per block. Combines the
// two proven facts: (a) per-wave 16-q-row body needs only 84 VGPR (R18
// measured); (b) 128-q-row blocks amortize the fixed 32KB K/V staging +
// 2 barriers/iter properly (R16). R18's loss (91->106us despite occupancy
// 18->28%) was block geometry: 2x blocks doubled total staging/barrier
// work for the same MFMA. Here staging per block is unchanged but serves
// 8 waves. The R9-R12 512-thr "VGPR pinned at 128" behavior is harmless:
// 84 < 128 -> no spill, and 128-budget = 4 waves/SIMD (2 blocks/CU at
// 32KB LDS) -> 2x R16's occupancy at R16's staging economy.
// Sync structure = R16's proven single-buffer restage:
//   top barrier [K landed] -> stageV -> QK^T + softmax (covers V latency)
//   -> vmcnt(0)+barrier [V visible] -> stageK(it+1) -> PV.
__global__ __launch_bounds__(512) void attn(
    const unsigned short* __restrict__ Q,
    const unsigned short* __restrict__ K,
    const unsigned short* __restrict__ Vt,
    const unsigned short* __restrict__ wmask,
    float* __restrict__ out) {
  __shared__ __align__(16) unsigned short Ks[128 * 64];   // [key][d], swizzled
  __shared__ __align__(16) unsigned short Vs[64 * 128];   // [d][key'], swizzled

  const int t = threadIdx.x;   // 0..511
  const int lane = t & 63;
  const int w = t >> 6;        // 0..7

  // XCD swizzle: all 16 q-tiles of a bh on one XCD
  const int n = blockIdx.x;          // 0..1023
  const int xcd = n & 7;
  const int li = n >> 3;             // 0..127
  const int bh = xcd * 8 + (li >> 4);
  const int qt = li & 15;

  const int b = bh >> 4, h = bh & 15;
  const int s0 = qt * 128;
  const unsigned short* Qp = Q + (size_t)bh * SEQ * DHEAD;
  const unsigned short* Kp = K + (size_t)bh * SEQ * DHEAD;
  const unsigned short* Vp = Vt + (size_t)bh * DHEAD * SEQ;
  const unsigned short* wmp = wmask + b * SEQ;

  const int cl = lane & 15;
  const int qd = lane >> 4;

  short8 qf[2];   // this wave's 16 q-rows: s0 + w*16 + cl
#pragma unroll
  for (int ks = 0; ks < 2; ks++)
    qf[ks] = *(const short8*)(Qp + (size_t)(s0 + w * 16 + cl) * DHEAD +
                              ks * 32 + qd * 8);

  f32x4 ov[4];   // [dt], D[d][q]: q=cl, d rows = dt*16+qd*4+r
  f32x4 ovl;     // l accumulator (sum_k w_k p_k), all rows identical
  ovl = (f32x4){0.f, 0.f, 0.f, 0.f};
#pragma unroll
  for (int dt = 0; dt < 4; dt++) ov[dt] = (f32x4){0.f, 0.f, 0.f, 0.f};

  // K tile 128x64 bf16 = 16KB: 512 thr x 2 gll16. Unit j covers rows
  // j*64..j*64+63; wave w stages rows j*64 + w*8 .. +7 (8 rows, linear).
  auto stageK = [&](int kt) {
#pragma unroll
    for (int j = 0; j < 2; j++) {
      int r0 = j * 64 + w * 8;
      int r = r0 + (lane >> 3);
      int c = (lane & 7) ^ (r & 7);
      gll16(Kp + (size_t)(kt + r) * DHEAD + c * 8, &Ks[r0 * 64]);
    }
  };
  // V tile 64x128 bf16 = 16KB: unit j covers rows j*32..j*32+31; wave w
  // stages rows j*32 + w*4 .. +3 (4 rows, 16 lanes/row).
  auto stageV = [&](int kt) {
#pragma unroll
    for (int j = 0; j < 2; j++) {
      int r0 = j * 32 + w * 4;
      int r = r0 + (lane >> 4);
      int c = (lane & 15) ^ (r & 7);
      gll16(Vp + (size_t)r * SEQ + kt + c * 8, &Vs[r0 * 128]);
    }
  };

  stageK(0);

  for (int it = 0; it < SEQ / 128; it++) {
    const int kt = it * 128;
    __syncthreads();      // K(it) landed+visible; prev PV reads done
    stageV(kt);           // V(it) -> Vs (async; used after softmax)

    // w A-fragment for l-MFMA: keys in P's permuted k-order
    short8 wf[4];
#pragma unroll
    for (int c = 0; c < 4; c++) {
      u32x2 w0 = *(const u32x2*)(wmp + kt + c * 32 + qd * 4);
      u32x2 w1 = *(const u32x2*)(wmp + kt + c * 32 + 16 + qd * 4);
      u32x4 ww = {w0[0], w0[1], w1[0], w1[1]};
      wf[c] = __builtin_bit_cast(short8, ww);
    }

    // ---- scores: D[m=key][n=q] ----
    f32x4 sc[8];
#pragma unroll
    for (int nt = 0; nt < 8; nt++) sc[nt] = (f32x4){0.f, 0.f, 0.f, 0.f};
#pragma unroll
    for (int ks = 0; ks < 2; ks++) {
#pragma unroll
      for (int nt = 0; nt < 8; nt++) {
        int krow = nt * 16 + cl;
        short8 kf = *(const short8*)(Ks + krow * 64 +
                                     (((ks * 4 + qd) ^ (krow & 7)) << 3));
        sc[nt] = __builtin_amdgcn_mfma_f32_16x16x32_bf16(kf, qf[ks], sc[nt], 0, 0, 0);
      }
    }

    // ---- softmax: p = exp2(s) ----
    unsigned pw[8][2];
#pragma unroll
    for (int nt = 0; nt < 8; nt++) {
      float p0 = __builtin_amdgcn_exp2f(sc[nt][0]);
      float p1 = __builtin_amdgcn_exp2f(sc[nt][1]);
      float p2 = __builtin_amdgcn_exp2f(sc[nt][2]);
      float p3 = __builtin_amdgcn_exp2f(sc[nt][3]);
      pw[nt][0] = pk2h(p0, p1);
      pw[nt][1] = pk2h(p2, p3);
    }

    // ---- V(it) landed + visible; then issue K(it+1) ----
    __builtin_amdgcn_sched_barrier(0);
    asm volatile("s_waitcnt vmcnt(0)");   // drains V (+wf; K not in flight)
    __builtin_amdgcn_sched_barrier(0);
    __builtin_amdgcn_s_barrier();         // all waves' V writes visible
    __builtin_amdgcn_sched_barrier(0);

    if (it + 1 < SEQ / 128) stageK(kt + 128);  // after all QK reads of Ks

    // ---- O += V' * P (permuted k-order; V from single-buffer LDS) ----
#pragma unroll
    for (int c = 0; c < 4; c++) {
      u32x4 bb0 = {pw[2 * c][0], pw[2 * c][1], pw[2 * c + 1][0], pw[2 * c + 1][1]};
      short8 bf0 = __builtin_bit_cast(short8, bb0);
      ovl = __builtin_amdgcn_mfma_f32_16x16x32_bf16(wf[c], bf0, ovl, 0, 0, 0);
#pragma unroll
      for (int dt = 0; dt < 4; dt++) {
        int vrow = dt * 16 + cl;
        short8 vf = *(const short8*)(Vs + vrow * 128 +
                                     (((c * 4 + qd) ^ (vrow & 7)) << 3));
        ov[dt] = __builtin_amdgcn_mfma_f32_16x16x32_bf16(vf, bf0, ov[dt], 0, 0, 0);
      }
    }
  }

  // ---- epilogue: O[d][q] / l(q) ----
  {
    float rl = 1.0f / ovl[0];
    int s = s0 + w * 16 + cl;
    float* ob = out + ((size_t)b * SEQ + s) * HD + h * DHEAD;
#pragma unroll
    for (int dt = 0; dt < 4; dt++) {
      f32x4 o;
      o[0] = ov[dt][0] * rl;
      o[1] = ov[dt][1] * rl;
      o[2] = ov[dt][2] * rl;
      o[3] = ov[dt][3] * rl;
      *(f32x4*)(ob + dt * 16 + qd * 4) = o;
    }
  }
}

extern "C" void kernel_launch(void* const* d_in, const int* in_sizes, int n_in,
                              void* d_out, int out_size, void* d_ws, size_t ws_size,
                              hipStream_t stream) {
  const float* hidden = (const float*)d_in[0];
  const float* mask   = (const float*)d_in[1];
  const float* rel    = (const float*)d_in[2];
  const float* Wq     = (const float*)d_in[3];
  const float* bq     = (const float*)d_in[4];
  const float* Wk     = (const float*)d_in[5];
  const float* bk     = (const float*)d_in[6];
  const float* Wv     = (const float*)d_in[7];
  const float* bv     = (const float*)d_in[8];
  float* out = (float*)d_out;

  unsigned short* Xb = (unsigned short*)d_ws;          // 8192*1024
  unsigned short* Wb = Xb + (size_t)MTOT * HD;         // 3*1024*1024
  unsigned short* Qb = Wb + (size_t)3 * HD * HD;       // 8192*1024
  unsigned short* Kb = Qb + (size_t)MTOT * HD;
  unsigned short* Vb = Kb + (size_t)MTOT * HD;
  unsigned short* Wm = Vb + (size_t)MTOT * HD;         // 4*2048

  {
    int n4 = MTOT * HD / 4;
    cvt_bf16<<<n4 / 256, 256, 0, stream>>>(hidden, Xb, n4);
  }
  prep<<<(3 * WQ4 + BATCH * SEQ / 4) / 256, 256, 0, stream>>>(Wq, Wk, Wv, mask, Wb, Wm);
  qkv_gemm<<<dim3(1536), 256, 0, stream>>>(Xb, Wb, bq, bk, bv, rel, mask, Qb, Kb, Vb);
  attn<<<dim3(1024), 512, 0, stream>>>(Qb, Kb, Vb, Wm, out);
}

// Round 17
// 248.162 us; speedup vs baseline: 1.0772x; 1.0355x over previous
//
#include <hip/hip_runtime.h>
#include <hip/hip_bf16.h>

typedef __attribute__((ext_vector_type(8))) short short8;
typedef __attribute__((ext_vector_type(4))) float f32x4;
typedef __attribute__((ext_vector_type(4))) unsigned int u32x4;
typedef __attribute__((ext_vector_type(2))) unsigned int u32x2;
typedef __attribute__((ext_vector_type(4))) unsigned short u16x4;

#define NHEADS 16
#define DHEAD 64
#define SEQ 2048
#define BATCH 4
#define HD 1024
#define MTOT 8192  // BATCH*SEQ

// RNE f32->bf16 (cold paths)
static __device__ __forceinline__ unsigned short f2b(float x) {
  unsigned u = __builtin_bit_cast(unsigned, x);
  u += 0x7fffu + ((u >> 16) & 1u);
  return (unsigned short)(u >> 16);
}

// round-half-up pack of two f32 -> bf16x2 (<=0.5 ulp, 4 insts; epilogues)
static __device__ __forceinline__ unsigned pk2h(float lo, float hi) {
  unsigned a = __builtin_bit_cast(unsigned, lo) + 0x8000u;
  unsigned b = __builtin_bit_cast(unsigned, hi) + 0x8000u;
  return (a >> 16) | (b & 0xffff0000u);
}

// R21: native bf16 pair pack for the attn softmax hot loop. Per m240,
// scalar HIP casts beat hand-written packing: on gfx950 the compiler
// lowers paired fptrunc-to-bf16 to v_cvt_pk_bf16_f32 (1 inst/pair vs
// pk2h's 4). attn VALU chain was the long pole (VALUBusy 44% > MfmaUtil
// 35%; 128 pack insts/wave-iter of ~512 VALU cycles).
static __device__ __forceinline__ unsigned pk2n(float lo, float hi) {
  unsigned short a = __builtin_bit_cast(unsigned short, __float2bfloat16(lo));
  unsigned short b = __builtin_bit_cast(unsigned short, __float2bfloat16(hi));
  return (unsigned)a | ((unsigned)b << 16);
}

// async global -> LDS, 16B per lane. LDS dst = wave-uniform base + lane*16.
// (R22 fix: this definition was accidentally dropped in the R21 edit ->
// compile failure; restored verbatim.)
static __device__ __forceinline__ void gll16(const void* g, void* l) {
  __builtin_amdgcn_global_load_lds(
      (const __attribute__((address_space(1))) unsigned int*)g,
      (__attribute__((address_space(3))) unsigned int*)l, 16, 0, 0);
}

// ---- merged prep: X f32->bf16, Wq/Wk/Wv -> bf16, wmask = bf16(exp(mask)) --
// R21: single launch (was cvt_bf16 + prep = 2 launches; pure launch-
// overhead cut, no per-element change).
#define XN4 (MTOT * HD / 4)  // 2097152 vec4s of X
#define WQ4 (HD * HD / 4)    // 262144 vec4s per weight matrix
__global__ void prep_all(const float* __restrict__ X,
                         const float* __restrict__ Wq,
                         const float* __restrict__ Wk,
                         const float* __restrict__ Wv,
                         const float* __restrict__ mask,
                         unsigned short* __restrict__ Xb,
                         unsigned short* __restrict__ Wb,
                         unsigned short* __restrict__ Wm) {
  int i = blockIdx.x * blockDim.x + threadIdx.x;
  if (i < XN4) {
    f32x4 v = ((const f32x4*)X)[i];
    u16x4 o;
    o[0] = f2b(v[0]); o[1] = f2b(v[1]); o[2] = f2b(v[2]); o[3] = f2b(v[3]);
    ((u16x4*)Xb)[i] = o;
  } else if (i < XN4 + 3 * WQ4) {
    int j = i - XN4;
    int rg = j / WQ4;
    int idx = j - rg * WQ4;
    const float* src = (rg == 0) ? Wq : (rg == 1) ? Wk : Wv;
    f32x4 v = ((const f32x4*)src)[idx];
    u16x4 o;
    o[0] = f2b(v[0]); o[1] = f2b(v[1]); o[2] = f2b(v[2]); o[3] = f2b(v[3]);
    ((u16x4*)(Wb + (size_t)rg * HD * HD))[idx] = o;
  } else {
    int j = i - XN4 - 3 * WQ4;      // 0..2047 vec4s of mask
    f32x4 v = ((const f32x4*)mask)[j];
    u16x4 o;
    o[0] = f2b(__expf(v[0])); o[1] = f2b(__expf(v[1]));
    o[2] = f2b(__expf(v[2])); o[3] = f2b(__expf(v[3]));
    ((u16x4*)Wm)[j] = o;
  }
}

// ------- fused QKV GEMM: 128x128, 256 thr, m97 single-buffer structure -----
// R16 (unchanged): SINGLE 32KB buffer, per K-step
//   {barrier -> stage 8 gll16/thr -> barrier(vmcnt0 drain) -> 32 MFMA};
// VGPR 108 + 32KB LDS -> 4 blocks/CU; drain stall of one block hides under
// other blocks' MFMA (m114 implicit overlap). Validated R16: qkv 96.5 -> <91.
// Per-wave (1M x 4N): 128 rows x 32 cols -> acc[8][2]=64 VGPR, bf[2][2]=16,
// af[2] transient -- fits the 128-VGPR/4-wave budget (R9-R12 lesson: bigger
// blocks get VGPR-pinned and spill; 256 thr allocates pressure-driven).
// R8 kept: m-slab XCD swizzle (8 m-tiles/XCD: X slab L2-resident, W panel
// fetched ~once/XCD -> FETCH 50MB), pre-swizzled-global gather so gll16's
// linear LDS write lands the XOR [row][slot s^=r&7] layout (0 conflicts).
__global__ __launch_bounds__(256) void qkv_gemm(
    const unsigned short* __restrict__ X,
    const unsigned short* __restrict__ Wall,
    const float* __restrict__ bq, const float* __restrict__ bk,
    const float* __restrict__ bv,
    const float* __restrict__ rel,          // [2048][64] f32
    const float* __restrict__ mask,         // [4][2048] f32
    unsigned short* __restrict__ Qo,
    unsigned short* __restrict__ Ko,
    unsigned short* __restrict__ Vt) {
  __shared__ __align__(16) unsigned short As[128 * 64];
  __shared__ __align__(16) unsigned short Bs[128 * 64];

  const int t = threadIdx.x;           // 0..255
  const int lane = t & 63;
  const int w = t >> 6;                // 0..3 == wn (N strip)

  // XCD swizzle: 8 m-tiles pinned per XCD (2MB X slab, L2-resident);
  // consecutive li share a panel so each W panel is fetched ~once per XCD.
  const int n = blockIdx.x;            // 0..1535
  const int xcd = n & 7;
  const int li = n >> 3;               // 0..191
  const int bx = xcd * 8 + (li & 7);   // m-tile 0..63
  const int pp = li >> 3;              // 0..23
  const int by = pp & 7;               // n-tile 0..7
  const int bz = pp >> 3;              // 0=Q 1=K 2=V

  const unsigned short* Wp = Wall + (size_t)bz * HD * HD;
  const int m0 = bx * 128;
  const int n0 = by * 128;

  const int cl = lane & 15;
  const int qd = lane >> 4;

  f32x4 acc[8][2];
#pragma unroll
  for (int i = 0; i < 8; i++)
#pragma unroll
    for (int j = 0; j < 2; j++) acc[i][j] = (f32x4){0.f, 0.f, 0.f, 0.f};

  // stage one 4KB unit = rows q*32..q*32+31, 64 k. Thread t -> row
  // q*32 + (t>>3), global chunk (t&7)^(row&7); LDS write is linear so
  // slot (t&7) at that row holds chunk (t&7)^(row&7) == XOR layout.
  auto stageA = [&](int q, int k0) {
    int rr = (q << 5) + (t >> 3);
    gll16(X + (size_t)(m0 + rr) * HD + k0 + (((t & 7) ^ (rr & 7)) << 3),
          &As[((q << 5) + (w << 3)) * 64]);
  };
  auto stageB = [&](int q, int k0) {
    int rr = (q << 5) + (t >> 3);
    gll16(Wp + (size_t)(n0 + rr) * HD + k0 + (((t & 7) ^ (rr & 7)) << 3),
          &Bs[((q << 5) + (w << 3)) * 64]);
  };

#pragma unroll 1
  for (int it = 0; it < 16; it++) {
    const int k0 = it * 64;
    __syncthreads();   // prev iter's LDS reads done before overwrite
    stageA(0, k0); stageA(1, k0); stageA(2, k0); stageA(3, k0);
    stageB(0, k0); stageB(1, k0); stageB(2, k0); stageB(3, k0);
    __syncthreads();   // drains vmcnt(0): tile landed + visible

    // bf for this wave's 32 B-rows, both K-halves (held through iter)
    short8 bf[2][2];
#pragma unroll
    for (int j = 0; j < 2; j++) {
      int r = w * 32 + j * 16 + cl;
      const unsigned short* rp = &Bs[r * 64];
#pragma unroll
      for (int ks = 0; ks < 2; ks++)
        bf[j][ks] = *(const short8*)(rp + (((ks * 4 + qd) ^ (r & 7)) << 3));
    }

    __builtin_amdgcn_s_setprio(1);
#pragma unroll
    for (int mq = 0; mq < 4; mq++) {
#pragma unroll
      for (int ks = 0; ks < 2; ks++) {
        short8 af[2];
#pragma unroll
        for (int i = 0; i < 2; i++) {
          int r = mq * 32 + i * 16 + cl;
          af[i] = *(const short8*)(&As[r * 64] +
                                   (((ks * 4 + qd) ^ (r & 7)) << 3));
        }
        if (bz < 2) {
#pragma unroll
          for (int i = 0; i < 2; i++)
#pragma unroll
            for (int j = 0; j < 2; j++)
              acc[mq * 2 + i][j] = __builtin_amdgcn_mfma_f32_16x16x32_bf16(
                  bf[j][ks], af[i], acc[mq * 2 + i][j], 0, 0, 0);
        } else {
#pragma unroll
          for (int i = 0; i < 2; i++)
#pragma unroll
            for (int j = 0; j < 2; j++)
              acc[mq * 2 + i][j] = __builtin_amdgcn_mfma_f32_16x16x32_bf16(
                  af[i], bf[j][ks], acc[mq * 2 + i][j], 0, 0, 0);
        }
      }
    }
    __builtin_amdgcn_s_setprio(0);
  }

  // ---- epilogue (per-wave 128 rows x 32 cols at (m0, n0 + w*32)) ----
  if (bz == 2) {
    // normal orientation: acc[mf][nf] = D[m(s)][n(feature)]
#pragma unroll
    for (int mf = 0; mf < 8; mf++) {
      int mb = m0 + mf * 16 + qd * 4;
      int bb = mb >> 11, ssb = mb & (SEQ - 1);
      f32x4 mk = *(const f32x4*)(mask + bb * SEQ + ssb);
      f32x4 w4;
#pragma unroll
      for (int r = 0; r < 4; r++) w4[r] = __expf(mk[r]);
      int colp = (ssb & ~31) | ((ssb & 12) << 1) | (((ssb >> 4) & 1) << 2);
#pragma unroll
      for (int nf = 0; nf < 2; nf++) {
        int feat = n0 + w * 32 + nf * 16 + cl;
        int hh = feat >> 6;
        int dd = feat & 63;
        float bn = bv[feat];
        u32x2 pk;
        pk[0] = pk2h((acc[mf][nf][0] + bn) * w4[0], (acc[mf][nf][1] + bn) * w4[1]);
        pk[1] = pk2h((acc[mf][nf][2] + bn) * w4[2], (acc[mf][nf][3] + bn) * w4[3]);
        *(u32x2*)(Vt + ((size_t)((bb * NHEADS + hh) * DHEAD + dd)) * SEQ + colp) = pk;
      }
    }
  } else {
    // transposed: acc[mf][nf] = D[n(feature)][m(s)]
    const float* bias = (bz == 0) ? bq : bk;
    unsigned short* Out = (bz == 0) ? Qo : Ko;
    const float qs = (bz == 0) ? 0.125f * 1.4426950408889634f : 1.0f;
#pragma unroll
    for (int nf = 0; nf < 2; nf++) {
      int feat0 = n0 + w * 32 + nf * 16 + qd * 4;
      int hh = feat0 >> 6;
      int ddb = feat0 & 63;
      f32x4 b4 = *(const f32x4*)(bias + feat0);
#pragma unroll
      for (int mf = 0; mf < 8; mf++) {
        int s = m0 + mf * 16 + cl;
        int bb = s >> 11, ss = s & (SEQ - 1);
        f32x4 rl = *(const f32x4*)(rel + ss * DHEAD + ddb);
        float x0 = acc[mf][nf][0] + b4[0];
        float x1 = acc[mf][nf][1] + b4[1];
        float x2 = acc[mf][nf][2] + b4[2];
        float x3 = acc[mf][nf][3] + b4[3];
        float y0 = (x0 * rl[1] - x1 * rl[0]) * qs;
        float y1 = (x1 * rl[1] + x0 * rl[0]) * qs;
        float y2 = (x2 * rl[3] - x3 * rl[2]) * qs;
        float y3 = (x3 * rl[3] + x2 * rl[2]) * qs;
        u32x2 pk;
        pk[0] = pk2h(y0, y1);
        pk[1] = pk2h(y2, y3);
        *(u32x2*)(Out + (((size_t)(bb * NHEADS + hh)) * SEQ + ss) * DHEAD + ddb) = pk;
      }
    }
  }
}

// ---------------- flash attention (R16 geometry, best measured) ----------
// Q: [64][2048][64] bf16 pre-scaled by 0.125*log2e; K: [64][2048][64] bf16;
// Vt: [64][64][2048] bf16 (columns permuted, mask-scaled); wm: [4][2048] bf16.
// out: [4][2048][1024] f32.  Softmax inner op = one exp2 per score.
//
// R21: revert to R16's 256-thr / 32-q-rows-per-wave geometry (best: 91.3us;
// R18/R20 showed occupancy 18->38% does NOT move MfmaUtil ~35% -- wave
// count is not the limiter, and 16-q-row waves halve the MFMA-per-LDS-read
// ratio: bank conflicts doubled). Only hot-loop change vs R16: pw packing
// uses pk2n (native cvt_pk path) to cut the VALU pack chain 4->1 inst/pair.
// Sync structure = R15/R16 single-buffer restage:
//   top barrier [K landed] -> stageV -> QK^T + softmax (covers V latency)
//   -> vmcnt(0)+barrier [V visible] -> stageK(it+1) -> PV.
__global__ __launch_bounds__(256, 2) void attn(
    const unsigned short* __restrict__ Q,
    const unsigned short* __restrict__ K,
    const unsigned short* __restrict__ Vt,
    const unsigned short* __restrict__ wmask,
    float* __restrict__ out) {
  __shared__ __align__(16) unsigned short Ks[128 * 64];   // [key][d], swizzled
  __shared__ __align__(16) unsigned short Vs[64 * 128];   // [d][key'], swizzled

  const int t = threadIdx.x;
  const int lane = t & 63;
  const int w = t >> 6;

  // XCD swizzle: all 16 q-tiles of a bh on one XCD
  const int n = blockIdx.x;          // 0..1023
  const int xcd = n & 7;
  const int li = n >> 3;             // 0..127
  const int bh = xcd * 8 + (li >> 4);
  const int qt = li & 15;

  const int b = bh >> 4, h = bh & 15;
  const int s0 = qt * 128;
  const unsigned short* Qp = Q + (size_t)bh * SEQ * DHEAD;
  const unsigned short* Kp = K + (size_t)bh * SEQ * DHEAD;
  const unsigned short* Vp = Vt + (size_t)bh * DHEAD * SEQ;
  const unsigned short* wmp = wmask + b * SEQ;

  const int cl = lane & 15;
  const int qd = lane >> 4;

  short8 qf[2][2];
#pragma unroll
  for (int mt = 0; mt < 2; mt++)
#pragma unroll
    for (int ks = 0; ks < 2; ks++)
      qf[mt][ks] = *(const short8*)(Qp + (size_t)(s0 + w * 32 + mt * 16 + cl) * DHEAD +
                                    ks * 32 + qd * 8);

  f32x4 ov[2][4];   // [mt][dt], D[d][q]: q=cl, d rows = dt*16+qd*4+r
  f32x4 ovl[2];     // l accumulator (sum_k w_k p_k), all rows identical
#pragma unroll
  for (int mt = 0; mt < 2; mt++) {
    ovl[mt] = (f32x4){0.f, 0.f, 0.f, 0.f};
#pragma unroll
    for (int dt = 0; dt < 4; dt++) ov[mt][dt] = (f32x4){0.f, 0.f, 0.f, 0.f};
  }

  auto stageK = [&](int kt) {
#pragma unroll
    for (int j = 0; j < 4; j++) {
      int r0 = w * 32 + j * 8;
      int r = r0 + (lane >> 3);
      int c = (lane & 7) ^ (r & 7);
      gll16(Kp + (size_t)(kt + r) * DHEAD + c * 8, &Ks[r0 * 64]);
    }
  };
  auto stageV = [&](int kt) {
#pragma unroll
    for (int j = 0; j < 4; j++) {
      int r0 = w * 16 + j * 4;
      int r = r0 + (lane >> 4);
      int c = (lane & 15) ^ (r & 7);
      gll16(Vp + (size_t)r * SEQ + kt + c * 8, &Vs[r0 * 128]);
    }
  };

  stageK(0);

  for (int it = 0; it < SEQ / 128; it++) {
    const int kt = it * 128;
    __syncthreads();      // K(it) landed+visible; prev PV reads done
    stageV(kt);           // V(it) -> Vs (async; used after softmax)

    // w A-fragment for l-MFMA: keys in P's permuted k-order
    short8 wf[4];
#pragma unroll
    for (int c = 0; c < 4; c++) {
      u32x2 w0 = *(const u32x2*)(wmp + kt + c * 32 + qd * 4);
      u32x2 w1 = *(const u32x2*)(wmp + kt + c * 32 + 16 + qd * 4);
      u32x4 ww = {w0[0], w0[1], w1[0], w1[1]};
      wf[c] = __builtin_bit_cast(short8, ww);
    }

    // ---- scores: D[m=key][n=q] ----
    f32x4 sc[2][8];
#pragma unroll
    for (int mt = 0; mt < 2; mt++)
#pragma unroll
      for (int nt = 0; nt < 8; nt++) sc[mt][nt] = (f32x4){0.f, 0.f, 0.f, 0.f};
#pragma unroll
    for (int ks = 0; ks < 2; ks++) {
#pragma unroll
      for (int nt = 0; nt < 8; nt++) {
        int krow = nt * 16 + cl;
        short8 kf = *(const short8*)(Ks + krow * 64 +
                                     (((ks * 4 + qd) ^ (krow & 7)) << 3));
        sc[0][nt] = __builtin_amdgcn_mfma_f32_16x16x32_bf16(kf, qf[0][ks], sc[0][nt], 0, 0, 0);
        sc[1][nt] = __builtin_amdgcn_mfma_f32_16x16x32_bf16(kf, qf[1][ks], sc[1][nt], 0, 0, 0);
      }
    }

    // ---- softmax: p = exp2(s); native pair pack (v_cvt_pk_bf16_f32) ----
    unsigned pw[2][8][2];
#pragma unroll
    for (int mt = 0; mt < 2; mt++) {
#pragma unroll
      for (int nt = 0; nt < 8; nt++) {
        float p0 = __builtin_amdgcn_exp2f(sc[mt][nt][0]);
        float p1 = __builtin_amdgcn_exp2f(sc[mt][nt][1]);
        float p2 = __builtin_amdgcn_exp2f(sc[mt][nt][2]);
        float p3 = __builtin_amdgcn_exp2f(sc[mt][nt][3]);
        pw[mt][nt][0] = pk2n(p0, p1);
        pw[mt][nt][1] = pk2n(p2, p3);
      }
    }

    // ---- V(it) landed + visible; then issue K(it+1) ----
    __builtin_amdgcn_sched_barrier(0);
    asm volatile("s_waitcnt vmcnt(0)");   // drains V (+wf; K not in flight)
    __builtin_amdgcn_sched_barrier(0);
    __builtin_amdgcn_s_barrier();         // all waves' V writes visible
    __builtin_amdgcn_sched_barrier(0);

    if (it + 1 < SEQ / 128) stageK(kt + 128);  // after all QK reads of Ks

    // ---- O += V' * P (permuted k-order; V from single-buffer LDS) ----
#pragma unroll
    for (int c = 0; c < 4; c++) {
      u32x4 bb0 = {pw[0][2 * c][0], pw[0][2 * c][1], pw[0][2 * c + 1][0], pw[0][2 * c + 1][1]};
      u32x4 bb1 = {pw[1][2 * c][0], pw[1][2 * c][1], pw[1][2 * c + 1][0], pw[1][2 * c + 1][1]};
      short8 bf0 = __builtin_bit_cast(short8, bb0);
      short8 bf1 = __builtin_bit_cast(short8, bb1);
      ovl[0] = __builtin_amdgcn_mfma_f32_16x16x32_bf16(wf[c], bf0, ovl[0], 0, 0, 0);
      ovl[1] = __builtin_amdgcn_mfma_f32_16x16x32_bf16(wf[c], bf1, ovl[1], 0, 0, 0);
#pragma unroll
      for (int dt = 0; dt < 4; dt++) {
        int vrow = dt * 16 + cl;
        short8 vf = *(const short8*)(Vs + vrow * 128 +
                                     (((c * 4 + qd) ^ (vrow & 7)) << 3));
        ov[0][dt] = __builtin_amdgcn_mfma_f32_16x16x32_bf16(vf, bf0, ov[0][dt], 0, 0, 0);
        ov[1][dt] = __builtin_amdgcn_mfma_f32_16x16x32_bf16(vf, bf1, ov[1][dt], 0, 0, 0);
      }
    }
  }

  // ---- epilogue: O[d][q] / l(q) ----
#pragma unroll
  for (int mt = 0; mt < 2; mt++) {
    float rl = 1.0f / ovl[mt][0];
    int s = s0 + w * 32 + mt * 16 + cl;
    float* ob = out + ((size_t)b * SEQ + s) * HD + h * DHEAD;
#pragma unroll
    for (int dt = 0; dt < 4; dt++) {
      f32x4 o;
      o[0] = ov[mt][dt][0] * rl;
      o[1] = ov[mt][dt][1] * rl;
      o[2] = ov[mt][dt][2] * rl;
      o[3] = ov[mt][dt][3] * rl;
      *(f32x4*)(ob + dt * 16 + qd * 4) = o;
    }
  }
}

extern "C" void kernel_launch(void* const* d_in, const int* in_sizes, int n_in,
                              void* d_out, int out_size, void* d_ws, size_t ws_size,
                              hipStream_t stream) {
  const float* hidden = (const float*)d_in[0];
  const float* mask   = (const float*)d_in[1];
  const float* rel    = (const float*)d_in[2];
  const float* Wq     = (const float*)d_in[3];
  const float* bq     = (const float*)d_in[4];
  const float* Wk     = (const float*)d_in[5];
  const float* bk     = (const float*)d_in[6];
  const float* Wv     = (const float*)d_in[7];
  const float* bv     = (const float*)d_in[8];
  float* out = (float*)d_out;

  unsigned short* Xb = (unsigned short*)d_ws;          // 8192*1024
  unsigned short* Wb = Xb + (size_t)MTOT * HD;         // 3*1024*1024
  unsigned short* Qb = Wb + (size_t)3 * HD * HD;       // 8192*1024
  unsigned short* Kb = Qb + (size_t)MTOT * HD;
  unsigned short* Vb = Kb + (size_t)MTOT * HD;
  unsigned short* Wm = Vb + (size_t)MTOT * HD;         // 4*2048

  prep_all<<<(XN4 + 3 * WQ4 + BATCH * SEQ / 4) / 256, 256, 0, stream>>>(
      hidden, Wq, Wk, Wv, mask, Xb, Wb, Wm);
  qkv_gemm<<<dim3(1536), 256, 0, stream>>>(Xb, Wb, bq, bk, bv, rel, mask, Qb, Kb, Vb);
  attn<<<dim3(1024), 256, 0, stream>>>(Qb, Kb, Vb, Wm, out);
}